// Round 7
// baseline (268.256 us; speedup 1.0000x reference)
//
#include <hip/hip_runtime.h>

#define K_DIM 8192
#define M_REAL 2000
#define N_REAL 2000
#define M_PAD 2048
#define N_PAD 2048

#define BM 256
#define BN 256
#define BK 32
#define SPLITK 4
#define KSLAB (K_DIM / SPLITK)   // 2048
#define NIT (KSLAB / BK)         // 64

// fused prep block ranges
#define NB_CONVW 16384           // 2048*8192/(4*256)
#define NB_CONVX 4096            // (8192/64) * (2048/64)
#define NB_INIT  3907            // ceil(2000*500/256)

typedef __bf16 bf16x8 __attribute__((ext_vector_type(8)));
typedef float f32x4 __attribute__((ext_vector_type(4)));
typedef float fvec4 __attribute__((ext_vector_type(4)));   // for nontemporal builtins

#define RAW_BARRIER()  asm volatile("s_barrier" ::: "memory")
#define WAIT_VM4()     asm volatile("s_waitcnt vmcnt(4)" ::: "memory")
#define WAIT_VM0()     asm volatile("s_waitcnt vmcnt(0)" ::: "memory")

// Bank-conflict swizzle: LDS rows are 64B (16 dwords), so bank position only
// depends on (row&1, 16B-chunk). f spreads 16 consecutive rows over all 8
// distinct (parity, chunk) combos exactly twice -> 2-way access = free (m136).
#define FSWZ(r) (((r) & 3) ^ (((r) >> 2) & 3))

__device__ __forceinline__ unsigned short f2bf(float f) {
    union { float f; unsigned u; } v; v.f = f;
    unsigned r = v.u + 0x7FFFu + ((v.u >> 16) & 1u);  // RNE; inputs are finite normals
    return (unsigned short)(r >> 16);
}

__device__ __forceinline__ void async16(const void* g, void* l) {
    __builtin_amdgcn_global_load_lds((__attribute__((address_space(1))) void*)(g),
                                     (__attribute__((address_space(3))) void*)(l),
                                     16, 0, 0);
}

// ---------------------------------------------------------------------------
// Fused prep — UNCHANGED from round 6 (control; should surface in top-5 now):
//   [0, NB_CONVW)       W f32 -> Wb bf16 [2048][8192]
//   [+NB_CONVX)         X [8192][2000] f32 -> XT bf16 [2048][8192] (transpose)
//   [+NB_INIT)          out[m][n] = bias[n]
__global__ __launch_bounds__(256) void prep_kernel(const float* __restrict__ W,
                                                   const float* __restrict__ X,
                                                   const float* __restrict__ bias,
                                                   unsigned short* __restrict__ Wb,
                                                   unsigned short* __restrict__ XT,
                                                   float* __restrict__ out) {
    __shared__ unsigned short tile[64][68];
    int bid = blockIdx.x;
    if (bid < NB_CONVW) {
        long long t = (long long)bid * 256 + threadIdx.x;
        long long e = t * 4;                  // 4 elements per thread
        int m = (int)(e >> 13);
        ushort4 o = make_ushort4(0, 0, 0, 0);
        if (m < M_REAL) {
            fvec4 f = __builtin_nontemporal_load((const fvec4*)(W + e));
            o.x = f2bf(f.x); o.y = f2bf(f.y); o.z = f2bf(f.z); o.w = f2bf(f.w);
        }
        *(ushort4*)(Wb + e) = o;
    } else if (bid < NB_CONVW + NB_CONVX) {
        int b2 = bid - NB_CONVW;
        int k0 = (b2 & 127) * 64;
        int n0 = (b2 >> 7) * 64;
        int t = threadIdx.x;
        int c16 = t & 15, r16 = t >> 4;
#pragma unroll
        for (int it = 0; it < 4; ++it) {
            int k = k0 + r16 + it * 16;
            int n = n0 + c16 * 4;
            fvec4 v = {0.f, 0.f, 0.f, 0.f};
            if (n < N_REAL)
                v = __builtin_nontemporal_load((const fvec4*)(X + (long long)k * N_REAL + n));
            ushort4 o;
            o.x = f2bf(v.x); o.y = f2bf(v.y); o.z = f2bf(v.z); o.w = f2bf(v.w);
            *(ushort4*)&tile[r16 + it * 16][c16 * 4] = o;
        }
        __syncthreads();
#pragma unroll
        for (int it = 0; it < 4; ++it) {
            int nn = r16 + it * 16;           // n - n0
            int k4 = c16 * 4;
            ushort4 o;
            o.x = tile[k4 + 0][nn];
            o.y = tile[k4 + 1][nn];
            o.z = tile[k4 + 2][nn];
            o.w = tile[k4 + 3][nn];
            *(ushort4*)(XT + (long long)(n0 + nn) * K_DIM + k0 + k4) = o;
        }
    } else {
        int t = (bid - NB_CONVW - NB_CONVX) * 256 + threadIdx.x;
        if (t < M_REAL * (N_REAL / 4)) {
            int m = t / (N_REAL / 4);
            int n4 = t - m * (N_REAL / 4);
            float4 bv = *(const float4*)(bias + n4 * 4);
            *(float4*)(out + (long long)m * N_REAL + n4 * 4) = bv;
        }
    }
}

// ---------------------------------------------------------------------------
// Split-K GEMM, 256x256 tile, BK=32, double-buffered LDS, raw s_barrier +
// vmcnt(4). NEW this round: XOR chunk swizzle kills the 8-way LDS bank
// conflict on ds_read_b128 (staging lanes fetch permuted 16B chunks of the
// same 64B k-line; readers XOR the chunk index back).
__global__ __launch_bounds__(512, 2) void gemm_kernel(const unsigned short* __restrict__ Wb,
                                                      const unsigned short* __restrict__ XT,
                                                      float* __restrict__ out) {
    __shared__ __align__(16) unsigned short As[2][BM * BK];  // 2 x 16 KB
    __shared__ __align__(16) unsigned short Bs[2][BN * BK];  // 2 x 16 KB

    int f = blockIdx.x;
    int xcd = f & 7;
    int local = f >> 3;                    // 0..31
    int bz = local & 3;
    int bx = (xcd & 3) * 2 + ((local >> 2) & 1);   // 0..7
    int by = (xcd >> 2) * 4 + (local >> 3);        // 0..7

    int t = threadIdx.x;
    int w = t >> 6;              // 0..7
    int l = t & 63;
    int wm = (w >> 2) * 128;     // 0 or 128
    int wn = (w & 3) * 64;       // 0,64,128,192
    int lane16 = l & 15;
    int quad = l >> 4;
    int m0 = by * BM;
    int n0 = bx * BN;
    int ks = bz * KSLAB;

    f32x4 acc[8][4] = {};

    // Staging: lane l -> LDS chunk (row = l>>2, c = l&3); it FETCHES global
    // chunk c ^ FSWZ(row) so LDS[row][c] = global[row][c ^ FSWZ(row%16)].
    int srow = l >> 2;
    int scol = ((l & 3) ^ FSWZ(srow)) * 8;   // element offset within k-line
    int rb = w * 32;
    const unsigned short* gA0 = Wb + (long long)(m0 + rb + srow) * K_DIM + ks + scol;
    const unsigned short* gA1 = gA0 + 16LL * K_DIM;
    const unsigned short* gB0 = XT + (long long)(n0 + rb + srow) * K_DIM + ks + scol;
    const unsigned short* gB1 = gB0 + 16LL * K_DIM;

    // Reader: wants global[row][quad]; it's stored at chunk quad ^ FSWZ(row%16),
    // and row%16 == lane16 (wm/wn/i*16 are multiples of 16).
    int rchunk = ((quad ^ FSWZ(lane16))) * 8;

    async16(gA0, &As[0][rb * BK]);
    async16(gA1, &As[0][(rb + 16) * BK]);
    async16(gB0, &Bs[0][rb * BK]);
    async16(gB1, &Bs[0][(rb + 16) * BK]);
    gA0 += BK; gA1 += BK; gB0 += BK; gB1 += BK;

    for (int kt = 0; kt < NIT; ++kt) {
        int cur = kt & 1;
        if (kt + 1 < NIT) {
            int nxt = cur ^ 1;
            async16(gA0, &As[nxt][rb * BK]);
            async16(gA1, &As[nxt][(rb + 16) * BK]);
            async16(gB0, &Bs[nxt][rb * BK]);
            async16(gB1, &Bs[nxt][(rb + 16) * BK]);
            gA0 += BK; gA1 += BK; gB0 += BK; gB1 += BK;
            WAIT_VM4();
        } else {
            WAIT_VM0();
        }
        RAW_BARRIER();

        bf16x8 a[8], b[4];
#pragma unroll
        for (int i = 0; i < 8; ++i)
            a[i] = *(const bf16x8*)&As[cur][(wm + i * 16 + lane16) * BK + rchunk];
#pragma unroll
        for (int j = 0; j < 4; ++j)
            b[j] = *(const bf16x8*)&Bs[cur][(wn + j * 16 + lane16) * BK + rchunk];

#pragma unroll
        for (int i = 0; i < 8; ++i)
#pragma unroll
            for (int j = 0; j < 4; ++j)
                acc[i][j] = __builtin_amdgcn_mfma_f32_16x16x32_bf16(a[i], b[j], acc[i][j], 0, 0, 0);

        if (kt + 1 < NIT)
            RAW_BARRIER();
    }

    // Epilogue: C/D layout col = lane&15, row = quad*4 + reg  [m89-verified]
#pragma unroll
    for (int j = 0; j < 4; ++j) {
        int n = n0 + wn + j * 16 + lane16;
        if (n >= N_REAL) continue;
#pragma unroll
        for (int i = 0; i < 8; ++i) {
            int mbase = m0 + wm + i * 16 + quad * 4;
#pragma unroll
            for (int r = 0; r < 4; ++r) {
                int m = mbase + r;
                if (m < M_REAL)
                    atomicAdd(&out[(long long)m * N_REAL + n], acc[i][j][r]);
            }
        }
    }
}

// ---------------------------------------------------------------------------
extern "C" void kernel_launch(void* const* d_in, const int* in_sizes, int n_in,
                              void* d_out, int out_size, void* d_ws, size_t ws_size,
                              hipStream_t stream) {
    const float* W    = (const float*)d_in[0];  // [2000][8192]
    const float* bias = (const float*)d_in[1];  // [2000]
    const float* X    = (const float*)d_in[2];  // [8192][2000]
    float* out = (float*)d_out;

    unsigned short* Wb = (unsigned short*)d_ws;                 // [2048][8192] bf16
    unsigned short* XT = Wb + (long long)M_PAD * K_DIM;         // [2048][8192] bf16

    prep_kernel<<<NB_CONVW + NB_CONVX + NB_INIT, 256, 0, stream>>>(W, X, bias, Wb, XT, out);

    gemm_kernel<<<(N_PAD / BN) * (M_PAD / BM) * SPLITK, 512, 0, stream>>>(Wb, XT, out);
}